// Round 4
// baseline (11514.867 us; speedup 1.0000x reference)
//
#include <hip/hip_runtime.h>

// Problem constants (from reference)
#define EDIM 256
#define SLEN 64
#define TLEN 512
#define NTHREADS 512
#define NWAVES 8

// ---- wave (64-lane) reductions ----
__device__ __forceinline__ float wred_sum(float v) {
#pragma unroll
    for (int m = 32; m > 0; m >>= 1) v += __shfl_xor(v, m, 64);
    return v;
}
__device__ __forceinline__ float wred_max(float v) {
#pragma unroll
    for (int m = 32; m > 0; m >>= 1) v = fmaxf(v, __shfl_xor(v, m, 64));
    return v;
}

// ---- block reductions (all NTHREADS must call; trailing sync protects scr reuse) ----
__device__ __forceinline__ float block_sum(float v, float* scr, int tid) {
    v = wred_sum(v);
    if ((tid & 63) == 0) scr[tid >> 6] = v;
    __syncthreads();
    if (tid == 0) {
        float s = scr[0];
#pragma unroll
        for (int i = 1; i < NWAVES; ++i) s += scr[i];
        scr[0] = s;
    }
    __syncthreads();
    float r = scr[0];
    __syncthreads();
    return r;
}
__device__ __forceinline__ float block_max(float v, float* scr, int tid) {
    v = wred_max(v);
    if ((tid & 63) == 0) scr[tid >> 6] = v;
    __syncthreads();
    if (tid == 0) {
        float s = scr[0];
#pragma unroll
        for (int i = 1; i < NWAVES; ++i) s = fmaxf(s, scr[i]);
        scr[0] = s;
    }
    __syncthreads();
    float r = scr[0];
    __syncthreads();
    return r;
}

__global__ __launch_bounds__(NTHREADS) void gru_decoder_kernel(
    const float* __restrict__ signal,       // [B,T,E] fp32
    const float* __restrict__ bases,        // [B,S,E] fp32
    const int* __restrict__ mask,           // [B,T] int32 (nonzero = masked)
    const float* __restrict__ Ww,           // [E,E]
    const float* __restrict__ Wb,           // [E]
    const float* __restrict__ lng,          // [2E]
    const float* __restrict__ lnb,          // [2E]
    const float* __restrict__ wih,          // [3E,2E]
    const float* __restrict__ bih,          // [3E]
    const float* __restrict__ whh,          // [3E,E]
    const float* __restrict__ bhh,          // [3E]
    const float* __restrict__ hinit,        // [E]
    float* __restrict__ out)                // [B,S,E] fp32
{
    const int b    = blockIdx.x;
    const int tid  = threadIdx.x;
    const int lane = tid & 63;
    const int wave = tid >> 6;

    __shared__ float h_s[EDIM];
    __shared__ float v_s[EDIM];
    __shared__ float p_s[TLEN];
    __shared__ float inp_s[2 * EDIM];
    __shared__ float inpn_s[2 * EDIM];
    __shared__ float gx_s[3 * EDIM];
    __shared__ float gh_s[3 * EDIM];
    __shared__ float ctxp_s[4 * EDIM];
    __shared__ float scr[NWAVES];

    const float* sigb  = signal + (size_t)b * TLEN * EDIM;
    const int*   maskb = mask + (size_t)b * TLEN;

    if (tid < EDIM) h_s[tid] = hinit[tid];
    __syncthreads();

    for (int s = 0; s < SLEN; ++s) {
        // hoist this lane's h fragment (h[lane*4 .. lane*4+3]) — valid through phase D
        float4 hv = *reinterpret_cast<const float4*>(&h_s[lane * 4]);

        // ---- Phase A: v = h @ Ww^T + Wb  (wave-per-row, 32 rows/wave) ----
#pragma unroll 4
        for (int r = 0; r < EDIM / NWAVES; ++r) {
            int j = wave * (EDIM / NWAVES) + r;
            float4 w = *reinterpret_cast<const float4*>(&Ww[j * EDIM + lane * 4]);
            float d = w.x * hv.x + w.y * hv.y + w.z * hv.z + w.w * hv.w;
            d = wred_sum(d);
            if (lane == 0) v_s[j] = d + Wb[j];
        }
        __syncthreads();

        // ---- Phase B: e[t] = v . signal[b,t,:] (+ mask), 64 rows/wave ----
        float4 vv = *reinterpret_cast<const float4*>(&v_s[lane * 4]);
#pragma unroll 4
        for (int r = 0; r < TLEN / NWAVES; ++r) {
            int t = wave * (TLEN / NWAVES) + r;
            float4 w = *reinterpret_cast<const float4*>(&sigb[t * EDIM + lane * 4]);
            float d = w.x * vv.x + w.y * vv.y + w.z * vv.z + w.w * vv.w;
            d = wred_sum(d);
            // masked -> -1e30 (finite; exp underflows to exactly 0; no inf/NaN path)
            if (lane == 0) p_s[t] = maskb[t] ? -1e30f : d;
        }
        __syncthreads();

        // ---- softmax over T=512 (thread t owns p_s[t]) ----
        float e0 = p_s[tid];
        float M  = block_max(e0, scr, tid);
        float ex = __expf(e0 - M);           // masked: exp(-1e30 - M) -> 0
        p_s[tid] = ex;
        float Ssum = block_sum(ex, scr, tid);
        float inv  = 1.0f / Ssum;

        // ---- Phase C: context[e] = sum_t p[t]*signal[t,e] * inv ----
        {
            int tq = tid >> 7;           // 4 t-quarters
            int e2 = (tid & 127) * 2;    // each thread owns an e-pair
            float a0 = 0.f, a1 = 0.f;
#pragma unroll 4
            for (int i = 0; i < TLEN / 4; ++i) {
                int t = tq * (TLEN / 4) + i;
                float p = p_s[t];
                float2 w = *reinterpret_cast<const float2*>(&sigb[t * EDIM + e2]);
                a0 += p * w.x;
                a1 += p * w.y;
            }
            ctxp_s[tq * EDIM + e2]     = a0;
            ctxp_s[tq * EDIM + e2 + 1] = a1;
        }
        if (tid >= EDIM) {  // x part of inp: bases[b,s,:]
            int k = tid - EDIM;
            inp_s[k] = bases[((size_t)b * SLEN + s) * EDIM + k];
        }
        __syncthreads();
        if (tid < EDIM) {
            float c = (ctxp_s[tid] + ctxp_s[EDIM + tid] + ctxp_s[2 * EDIM + tid] + ctxp_s[3 * EDIM + tid]) * inv;
            inp_s[EDIM + tid] = c;
        }
        __syncthreads();

        // ---- LayerNorm over 2E=512 ----
        float val = inp_s[tid];
        float mu  = block_sum(val, scr, tid) * (1.0f / (2 * EDIM));
        float dv  = val - mu;
        float var = block_sum(dv * dv, scr, tid) * (1.0f / (2 * EDIM));
        float rs  = rsqrtf(var + 1e-5f);
        inpn_s[tid] = dv * rs * lng[tid] + lnb[tid];
        __syncthreads();

        // ---- Phase D: GRU matvecs (wave-per-row, 96 rows/wave each) ----
        float in8[8];
#pragma unroll
        for (int c = 0; c < 8; ++c) in8[c] = inpn_s[lane * 8 + c];
#pragma unroll 4
        for (int r = 0; r < 3 * EDIM / NWAVES; ++r) {
            int j = wave * (3 * EDIM / NWAVES) + r;
            const float* wr = &wih[j * (2 * EDIM) + lane * 8];
            float4 w0 = *reinterpret_cast<const float4*>(wr);
            float4 w1 = *reinterpret_cast<const float4*>(wr + 4);
            float d = w0.x * in8[0] + w0.y * in8[1] + w0.z * in8[2] + w0.w * in8[3]
                    + w1.x * in8[4] + w1.y * in8[5] + w1.z * in8[6] + w1.w * in8[7];
            d = wred_sum(d);
            if (lane == 0) gx_s[j] = d + bih[j];
        }
#pragma unroll 4
        for (int r = 0; r < 3 * EDIM / NWAVES; ++r) {
            int j = wave * (3 * EDIM / NWAVES) + r;
            float4 w = *reinterpret_cast<const float4*>(&whh[j * EDIM + lane * 4]);
            float d = w.x * hv.x + w.y * hv.y + w.z * hv.z + w.w * hv.w;
            d = wred_sum(d);
            if (lane == 0) gh_s[j] = d + bhh[j];
        }
        __syncthreads();

        // ---- Phase E: gates, h update, output (torch gate order r,z,n) ----
        if (tid < EDIM) {
            int j = tid;
            float r = 1.0f / (1.0f + __expf(-(gx_s[j] + gh_s[j])));
            float z = 1.0f / (1.0f + __expf(-(gx_s[EDIM + j] + gh_s[EDIM + j])));
            float n = tanhf(gx_s[2 * EDIM + j] + r * gh_s[2 * EDIM + j]);
            float hn = (1.0f - z) * n + z * h_s[j];
            h_s[j] = hn;
            out[((size_t)b * SLEN + s) * EDIM + j] = hn;
        }
        __syncthreads();
    }
}

extern "C" void kernel_launch(void* const* d_in, const int* in_sizes, int n_in,
                              void* d_out, int out_size, void* d_ws, size_t ws_size,
                              hipStream_t stream) {
    const float* signal = (const float*)d_in[0];
    const float* bases  = (const float*)d_in[1];
    const int*   mask   = (const int*)d_in[2];
    const float* Ww     = (const float*)d_in[3];
    const float* Wb     = (const float*)d_in[4];
    const float* lng    = (const float*)d_in[5];
    const float* lnb    = (const float*)d_in[6];
    const float* wih    = (const float*)d_in[7];
    const float* bih    = (const float*)d_in[8];
    const float* whh    = (const float*)d_in[9];
    const float* bhh    = (const float*)d_in[10];
    const float* hinit  = (const float*)d_in[11];
    float*       out    = (float*)d_out;

    const int B = in_sizes[0] / (TLEN * EDIM);   // 128

    gru_decoder_kernel<<<dim3(B), dim3(NTHREADS), 0, stream>>>(
        signal, bases, mask, Ww, Wb, lng, lnb, wih, bih, whh, bhh, hinit, out);
}

// Round 5
// 3530.881 us; speedup vs baseline: 3.2612x; 3.2612x over previous
//
#include <hip/hip_runtime.h>

// Problem constants (from reference)
#define EDIM 256
#define SLEN 64
#define TLEN 512
#define NTHREADS 512
#define NWAVES 8

// ---- wave (64-lane) reductions (only used for softmax/LN block reductions) ----
__device__ __forceinline__ float wred_sum(float v) {
#pragma unroll
    for (int m = 32; m > 0; m >>= 1) v += __shfl_xor(v, m, 64);
    return v;
}
__device__ __forceinline__ float wred_max(float v) {
#pragma unroll
    for (int m = 32; m > 0; m >>= 1) v = fmaxf(v, __shfl_xor(v, m, 64));
    return v;
}
__device__ __forceinline__ float block_sum(float v, float* scr, int tid) {
    v = wred_sum(v);
    if ((tid & 63) == 0) scr[tid >> 6] = v;
    __syncthreads();
    if (tid == 0) {
        float s = scr[0];
#pragma unroll
        for (int i = 1; i < NWAVES; ++i) s += scr[i];
        scr[0] = s;
    }
    __syncthreads();
    float r = scr[0];
    __syncthreads();
    return r;
}
__device__ __forceinline__ float block_max(float v, float* scr, int tid) {
    v = wred_max(v);
    if ((tid & 63) == 0) scr[tid >> 6] = v;
    __syncthreads();
    if (tid == 0) {
        float s = scr[0];
#pragma unroll
        for (int i = 1; i < NWAVES; ++i) s = fmaxf(s, scr[i]);
        scr[0] = s;
    }
    __syncthreads();
    float r = scr[0];
    __syncthreads();
    return r;
}

// ---- batched tiled transpose: out[z][c][r] = in[z][r][c], dims multiples of 64 ----
__global__ __launch_bounds__(256) void transpose_b_kernel(
    const float* __restrict__ in, float* __restrict__ out, int R, int C)
{
    __shared__ float tile[64][65];
    const float* inb = in + (size_t)blockIdx.z * R * C;
    float* outb = out + (size_t)blockIdx.z * R * C;
    const int r0 = blockIdx.y * 64;
    const int c0 = blockIdx.x * 64;
#pragma unroll
    for (int i = threadIdx.x; i < 64 * 64; i += 256) {
        int r = i >> 6, c = i & 63;
        tile[r][c] = inb[(size_t)(r0 + r) * C + (c0 + c)];
    }
    __syncthreads();
#pragma unroll
    for (int i = threadIdx.x; i < 64 * 64; i += 256) {
        int c = i >> 6, r = i & 63;       // consecutive i -> consecutive r -> coalesced store
        outb[(size_t)(c0 + c) * R + (r0 + r)] = tile[r][c];
    }
}

__global__ __launch_bounds__(NTHREADS) void gru_decoder_kernel(
    const float* __restrict__ signal,       // [B,T,E] fp32 (original layout, for phase C)
    const float* __restrict__ sigT,         // [B,E,T] fp32 (transposed, for phase B)
    const float* __restrict__ bases,        // [B,S,E]
    const int* __restrict__ mask,           // [B,T] int32 (nonzero = masked)
    const float* __restrict__ WwT,          // [E,E]   (WwT[k][j] = Ww[j][k])
    const float* __restrict__ Wb,           // [E]
    const float* __restrict__ lng,          // [2E]
    const float* __restrict__ lnb,          // [2E]
    const float* __restrict__ wihT,         // [2E,3E] (wihT[k][j] = wih[j][k])
    const float* __restrict__ bih,          // [3E]
    const float* __restrict__ whhT,         // [E,3E]
    const float* __restrict__ bhh,          // [3E]
    const float* __restrict__ hinit,        // [E]
    float* __restrict__ out)                // [B,S,E]
{
    const int b   = blockIdx.x;
    const int tid = threadIdx.x;

    __shared__ float h_s[EDIM];
    __shared__ float v_s[EDIM];
    __shared__ float vap[2 * EDIM];     // phase A k-split partials
    __shared__ float p_s[TLEN];
    __shared__ float cxp[2 * EDIM];     // phase C t-split partials
    __shared__ float inp_s[2 * EDIM];
    __shared__ float inpn_s[2 * EDIM];
    __shared__ float gxp[2 * 3 * EDIM]; // phase D k-split partials (gx)
    __shared__ float ghp[2 * 3 * EDIM]; // phase D k-split partials (gh)
    __shared__ float scr[NWAVES];

    const float* sigb  = signal + (size_t)b * TLEN * EDIM;
    const float* sigTb = sigT + (size_t)b * EDIM * TLEN;
    const int*   maskb = mask + (size_t)b * TLEN;

    if (tid < EDIM) h_s[tid] = hinit[tid];
    __syncthreads();

    for (int s = 0; s < SLEN; ++s) {
        // ---- Phase A: v = Ww @ h + Wb. Worker tid: half=k-split, row=output.
        {
            const int half = tid >> 8;           // 0/1 -> k in [half*128, half*128+128)
            const int row  = tid & 255;
            const float* col = WwT + (half * 128) * EDIM + row;
            const float* xk  = &h_s[half * 128];
            float acc = 0.f;
#pragma unroll 16
            for (int k = 0; k < 128; ++k)
                acc += col[k * EDIM] * xk[k];    // coalesced global + LDS broadcast
            vap[tid] = acc;
        }
        __syncthreads();
        if (tid < EDIM) v_s[tid] = vap[tid] + vap[EDIM + tid] + Wb[tid];
        __syncthreads();

        // ---- Phase B: e[t] = v . sig[t] via sigT (thread-per-t, coalesced) ----
        {
            const float* colT = sigTb + tid;     // sigT[k][tid]
            float acc = 0.f;
#pragma unroll 16
            for (int k = 0; k < EDIM; ++k)
                acc += colT[k * TLEN] * v_s[k];
            p_s[tid] = maskb[tid] ? -1e30f : acc;
        }
        // ---- softmax over T=512 ----
        float e0 = p_s[tid];
        float M  = block_max(e0, scr, tid);      // contains syncs
        float ex = __expf(e0 - M);
        p_s[tid] = ex;
        float Ssum = block_sum(ex, scr, tid);
        float inv  = 1.0f / Ssum;

        // ---- Phase C: ctx[e] = sum_t p[t]*sig[t][e] (thread-per-e, t-split) ----
        {
            const int half = tid >> 8;           // t in [half*256, half*256+256)
            const int e    = tid & 255;
            const float* col = sigb + (size_t)(half * 256) * EDIM + e;
            const float* pk  = &p_s[half * 256];
            float acc = 0.f;
#pragma unroll 16
            for (int t = 0; t < 256; ++t)
                acc += col[t * EDIM] * pk[t];    // coalesced global + LDS broadcast
            cxp[tid] = acc;
        }
        if (tid < EDIM) inp_s[tid] = bases[((size_t)b * SLEN + s) * EDIM + tid];
        __syncthreads();
        if (tid >= EDIM) {
            int e = tid - EDIM;
            inp_s[EDIM + e] = (cxp[e] + cxp[EDIM + e]) * inv;
        }
        __syncthreads();

        // ---- LayerNorm over 2E=512 ----
        float val = inp_s[tid];
        float mu  = block_sum(val, scr, tid) * (1.0f / (2 * EDIM));
        float dv  = val - mu;
        float var = block_sum(dv * dv, scr, tid) * (1.0f / (2 * EDIM));
        float rs  = rsqrtf(var + 1e-5f);
        inpn_s[tid] = dv * rs * lng[tid] + lnb[tid];
        __syncthreads();

        // ---- Phase D: gx = wih @ inpn (768x512), gh = whh @ h (768x256) ----
        // workers w = half*768 + row; each wave's 64 workers share one half (768 = 12*64)
#pragma unroll
        for (int wi = 0; wi < 3; ++wi) {
            int w = tid + wi * NTHREADS;
            int half = (w >= 768) ? 1 : 0;
            int row  = w - half * 768;
            {
                const float* col = wihT + (half * 256) * (3 * EDIM) + row;
                const float* xk  = &inpn_s[half * 256];
                float acc = 0.f;
#pragma unroll 16
                for (int k = 0; k < 256; ++k)
                    acc += col[k * (3 * EDIM)] * xk[k];
                gxp[w] = acc;
            }
            {
                const float* col = whhT + (half * 128) * (3 * EDIM) + row;
                const float* xk  = &h_s[half * 128];
                float acc = 0.f;
#pragma unroll 16
                for (int k = 0; k < 128; ++k)
                    acc += col[k * (3 * EDIM)] * xk[k];
                ghp[w] = acc;
            }
        }
        __syncthreads();

        // ---- Phase E: gates, h update, output (torch gate order r,z,n) ----
        if (tid < EDIM) {
            int j = tid;
            float xr = gxp[j]           + gxp[768 + j]           + bih[j];
            float xz = gxp[256 + j]     + gxp[768 + 256 + j]     + bih[256 + j];
            float xn = gxp[512 + j]     + gxp[768 + 512 + j]     + bih[512 + j];
            float hr = ghp[j]           + ghp[768 + j]           + bhh[j];
            float hz = ghp[256 + j]     + ghp[768 + 256 + j]     + bhh[256 + j];
            float hnn= ghp[512 + j]     + ghp[768 + 512 + j]     + bhh[512 + j];
            float r = 1.0f / (1.0f + __expf(-(xr + hr)));
            float z = 1.0f / (1.0f + __expf(-(xz + hz)));
            float n = tanhf(xn + r * hnn);
            float hnew = (1.0f - z) * n + z * h_s[j];
            h_s[j] = hnew;
            out[((size_t)b * SLEN + s) * EDIM + j] = hnew;
        }
        __syncthreads();
    }
}

extern "C" void kernel_launch(void* const* d_in, const int* in_sizes, int n_in,
                              void* d_out, int out_size, void* d_ws, size_t ws_size,
                              hipStream_t stream) {
    const float* signal = (const float*)d_in[0];
    const float* bases  = (const float*)d_in[1];
    const int*   mask   = (const int*)d_in[2];
    const float* Ww     = (const float*)d_in[3];
    const float* Wb     = (const float*)d_in[4];
    const float* lng    = (const float*)d_in[5];
    const float* lnb    = (const float*)d_in[6];
    const float* wih    = (const float*)d_in[7];
    const float* bih    = (const float*)d_in[8];
    const float* whh    = (const float*)d_in[9];
    const float* bhh    = (const float*)d_in[10];
    const float* hinit  = (const float*)d_in[11];
    float*       out    = (float*)d_out;

    const int B = in_sizes[0] / (TLEN * EDIM);   // 128

    // workspace layout (fp32): sigT[B,E,T] | WwT[E,E] | wihT[2E,3E] | whhT[E,3E]
    float* sigT = (float*)d_ws;
    float* WwT  = sigT + (size_t)B * EDIM * TLEN;
    float* wihT = WwT + EDIM * EDIM;
    float* whhT = wihT + (2 * EDIM) * (3 * EDIM);

    // pre-pass transposes (re-run every call; ws is re-poisoned by harness)
    transpose_b_kernel<<<dim3(EDIM / 64, TLEN / 64, B), 256, 0, stream>>>(signal, sigT, TLEN, EDIM);
    transpose_b_kernel<<<dim3(EDIM / 64, EDIM / 64, 1), 256, 0, stream>>>(Ww, WwT, EDIM, EDIM);
    transpose_b_kernel<<<dim3(2 * EDIM / 64, 3 * EDIM / 64, 1), 256, 0, stream>>>(wih, wihT, 3 * EDIM, 2 * EDIM);
    transpose_b_kernel<<<dim3(EDIM / 64, 3 * EDIM / 64, 1), 256, 0, stream>>>(whh, whhT, 3 * EDIM, EDIM);

    gru_decoder_kernel<<<dim3(B), dim3(NTHREADS), 0, stream>>>(
        signal, sigT, bases, mask, WwT, Wb, lng, lnb, wihT, bih, whhT, bhh, hinit, out);
}